// Round 7
// baseline (291.073 us; speedup 1.0000x reference)
//
#include <hip/hip_runtime.h>
#include <math.h>

typedef __bf16 bf16;
typedef __bf16 bf16x4 __attribute__((ext_vector_type(4)));
typedef __bf16 bf16x8 __attribute__((ext_vector_type(8)));
typedef float  f32x4  __attribute__((ext_vector_type(4)));
typedef unsigned short u16;

#define MFMA16(a, b, c) __builtin_amdgcn_mfma_f32_16x16x32_bf16((a), (b), (c), 0, 0, 0)

constexpr int Bz    = 4;
constexpr int Ts    = 2048;
constexpr int DM    = 1024;
constexpr int NH    = 16;
constexpr int HS    = 64;
constexpr int MROWS = Bz * Ts;   // 8192
constexpr int NQKV  = 3 * DM;    // 3072

// 0.125 (1/sqrt(64)) * log2(e): folded into Q at the QKV-GEMM epilogue.
#define QSCALE 0.18033688011112042f

__device__ __forceinline__ unsigned int pack2(bf16 lo, bf16 hi) {
    return ((unsigned int)__builtin_bit_cast(u16, hi) << 16) |
            (unsigned int)__builtin_bit_cast(u16, lo);
}

// ---------------------------------------------------------------------------
__device__ __forceinline__ void load_lds16(const bf16* g, bf16* l) {
    __builtin_amdgcn_global_load_lds(
        (__attribute__((address_space(1))) void*)(g),
        (__attribute__((address_space(3))) void*)(l), 16, 0, 0);
}

// ---------------------------------------------------------------------------
__global__ void cvt_kernel(const float* __restrict__ in, bf16* __restrict__ out, int n4) {
    int i = blockIdx.x * blockDim.x + threadIdx.x;
    if (i < n4) {
        float4 v = ((const float4*)in)[i];
        bf16x4 o = { (bf16)v.x, (bf16)v.y, (bf16)v.z, (bf16)v.w };
        ((bf16x4*)out)[i] = o;
    }
}

// ---------------------------------------------------------------------------
// C = A * B^T + bias.  128x128 tile, BK=32, 256 threads (m97 structure).
template <int OUT_BF16>
__global__ __launch_bounds__(256) void gemm_bt(const bf16* __restrict__ A,
                                               const bf16* __restrict__ Bw,
                                               const float* __restrict__ bias,
                                               void* __restrict__ Cout,
                                               int M, int N, int K,
                                               float qscale, int qcols)
{
    __shared__ __align__(16) bf16 As[128 * 32];
    __shared__ __align__(16) bf16 Bs[128 * 32];

    const int tid  = threadIdx.x;
    const int wave = tid >> 6, lane = tid & 63;
    const int quad = lane >> 4, l16 = lane & 15;
    const int wm = (wave >> 1) * 64, wn = (wave & 1) * 64;
    const int m0 = blockIdx.x * 128, n0 = blockIdx.y * 128;

    f32x4 acc[4][4] = {};

    const int c0 = tid, c1 = tid + 256;
    const bf16* gA0 = A  + (size_t)(m0 + (c0 >> 2)) * K + (c0 & 3) * 8;
    const bf16* gA1 = A  + (size_t)(m0 + (c1 >> 2)) * K + (c1 & 3) * 8;
    const bf16* gB0 = Bw + (size_t)(n0 + (c0 >> 2)) * K + (c0 & 3) * 8;
    const bf16* gB1 = Bw + (size_t)(n0 + (c1 >> 2)) * K + (c1 & 3) * 8;
    bf16* lA0 = As + c0 * 8;  bf16* lA1 = As + c1 * 8;
    bf16* lB0 = Bs + c0 * 8;  bf16* lB1 = Bs + c1 * 8;

    for (int kb = 0; kb < K; kb += 32) {
        if (kb) __syncthreads();
        load_lds16(gA0 + kb, lA0);
        load_lds16(gA1 + kb, lA1);
        load_lds16(gB0 + kb, lB0);
        load_lds16(gB1 + kb, lB1);
        __syncthreads();

        bf16x8 af[4], bfr[4];
#pragma unroll
        for (int mt = 0; mt < 4; ++mt)
            af[mt] = *(const bf16x8*)(As + (wm + mt * 16 + l16) * 32 + quad * 8);
#pragma unroll
        for (int nt = 0; nt < 4; ++nt)
            bfr[nt] = *(const bf16x8*)(Bs + (wn + nt * 16 + l16) * 32 + quad * 8);
#pragma unroll
        for (int mt = 0; mt < 4; ++mt)
#pragma unroll
            for (int nt = 0; nt < 4; ++nt)
                acc[mt][nt] = MFMA16(af[mt], bfr[nt], acc[mt][nt]);
    }

#pragma unroll
    for (int mt = 0; mt < 4; ++mt)
#pragma unroll
        for (int nt = 0; nt < 4; ++nt) {
            const int row = m0 + wm + mt * 16 + quad * 4;
            const int col = n0 + wn + nt * 16 + l16;
            const float bc = bias[col];
            const float sc = (col < qcols) ? qscale : 1.0f;
#pragma unroll
            for (int r = 0; r < 4; ++r) {
                const float v = (acc[mt][nt][r] + bc) * sc;
                if (OUT_BF16) ((bf16*)Cout)[(size_t)(row + r) * N + col] = (bf16)v;
                else          ((float*)Cout)[(size_t)(row + r) * N + col] = v;
            }
        }
}

// ---------------------------------------------------------------------------
// Vt key-block swizzle keyed on d>>3 (round-5-verified).
__device__ __forceinline__ int vswz(int d) { return ((d >> 3) & 7) << 3; }

// Flash attention, S^T formulation, 64-key tiles, software-pipelined staging.
// Block = (pair p, head, batch); q-tiles qt=p, 31-p (33 iters total).
// Ks double-buffered + async DMA (chunk-swizzled, round-6-verified read map);
// V prefetched into registers during compute, written to Vt between barriers.
// l accumulated via ones-row MFMA (no per-iter sum tree).
__global__ __launch_bounds__(256) void attn_kernel(const bf16* __restrict__ qkv,
                                                   bf16* __restrict__ y)
{
    __shared__ __align__(16) bf16 Ks[2][64 * 64];  // [buf][key][chunk-swizzled d]
    __shared__ __align__(16) bf16 Vt[64][72];      // [d][key ^ vswz(d)]
    __shared__ __align__(16) bf16 Ps[4][16][72];   // per-wave [q=l16][key]

    const int p = blockIdx.x, h = blockIdx.y, b = blockIdx.z;
    const int tid  = threadIdx.x;
    const int wave = tid >> 6, lane = tid & 63;
    const int quad = lane >> 4, l16 = lane & 15;

    const bf16* kbase = qkv + (size_t)(b * Ts) * NQKV + DM     + h * HS;
    const bf16* vbase = qkv + (size_t)(b * Ts) * NQKV + 2 * DM + h * HS;

    const int dg = tid & 7, kp = tid >> 3;        // staging decomposition
    const int k0 = 2 * kp;                        // V: thread's key pair
    const int krow = tid >> 3;                    // K: staging row (0..31, +32)
    const int ksrc = ((tid & 7) ^ (krow & 7)) * 8;// K: swizzled source chunk
    const int swr = (l16 & 7);                    // K: read-side swizzle

    const bf16 o1 = (l16 == 0) ? (bf16)1.0f : (bf16)0.0f;
    const bf16x8 ones = { o1, o1, o1, o1, o1, o1, o1, o1 };

    for (int phase = 0; phase < 2; ++phase) {
        const int qt = phase ? (31 - p) : p;
        const int qw = qt * 64 + wave * 16;
        const int q_abs = qw + l16;

        const bf16* qrow = qkv + (size_t)(b * Ts + qw + l16) * NQKV + h * HS;
        const bf16x8 qf0 = *(const bf16x8*)(qrow + quad * 8);
        const bf16x8 qf1 = *(const bf16x8*)(qrow + 32 + quad * 8);

        f32x4 o[4] = {};            // O^T[d = dt*16 + quad*4 + r][q = l16]
        f32x4 o_l = {};             // ones-row accumulator: reg0/quad0 = l[q]
        float m_run = -1e30f;

        // ---- prologue: prefetch tile 0 (barrier protects Ks[0] from prior phase)
        __syncthreads();
        {
            const bf16* gK = kbase + (size_t)krow * NQKV + ksrc;
            bf16* lK = &Ks[0][tid * 8];
            load_lds16(gK, lK);
            load_lds16(gK + (size_t)32 * NQKV, lK + 2048);
        }
        bf16x8 vr0 = *(const bf16x8*)(vbase + (size_t)k0 * NQKV + dg * 8);
        bf16x8 vr1 = *(const bf16x8*)(vbase + (size_t)(k0 + 1) * NQKV + dg * 8);

        for (int kt = 0; kt <= qt; ++kt) {
            const int cur = kt & 1;
            __syncthreads();   // TOP: drains DMA(kt)+vloads(kt); prior compute done

            // ---- Vt from prefetched regs: 8 packed b32 writes
#pragma unroll
            for (int j = 0; j < 8; ++j) {
                const int d = dg * 8 + j;
                *(unsigned int*)&Vt[d][k0 ^ vswz(d)] = pack2(vr0[j], vr1[j]);
            }
            __syncthreads();   // MID: Vt visible; Ks[cur] already drained at TOP

            // ---- prefetch tile kt+1 during compute (overlaps everything below)
            if (kt < qt) {
                const bf16* gK = kbase + (size_t)((kt + 1) * 64 + krow) * NQKV + ksrc;
                bf16* lK = &Ks[cur ^ 1][tid * 8];
                load_lds16(gK, lK);
                load_lds16(gK + (size_t)32 * NQKV, lK + 2048);
                vr0 = *(const bf16x8*)(vbase + (size_t)((kt + 1) * 64 + k0) * NQKV + dg * 8);
                vr1 = *(const bf16x8*)(vbase + (size_t)((kt + 1) * 64 + k0 + 1) * NQKV + dg * 8);
            }

            // ---- S^T (log2 domain), swizzled Ks reads
            f32x4 s[4];
#pragma unroll
            for (int sub = 0; sub < 4; ++sub) {
                const bf16* kr = &Ks[cur][(sub * 16 + l16) * 64];
                bf16x8 kf0 = *(const bf16x8*)(kr + (quad ^ swr) * 8);
                bf16x8 kf1 = *(const bf16x8*)(kr + ((4 + quad) ^ swr) * 8);
                f32x4 z = {};
                z = MFMA16(kf0, qf0, z);
                z = MFMA16(kf1, qf1, z);
                s[sub] = z;
            }

            // ---- causal mask (diagonal tile only)
            if (kt == qt) {
#pragma unroll
                for (int sub = 0; sub < 4; ++sub) {
                    const int kb = kt * 64 + sub * 16 + quad * 4;
#pragma unroll
                    for (int r = 0; r < 4; ++r)
                        if (kb + r > q_abs) s[sub][r] = -1e30f;
                }
            }

            // ---- online softmax (log2 domain); l handled by ones-MFMA
            float mA = fmaxf(fmaxf(s[0][0], s[0][1]), fmaxf(s[0][2], s[0][3]));
            float mB = fmaxf(fmaxf(s[1][0], s[1][1]), fmaxf(s[1][2], s[1][3]));
            float mC = fmaxf(fmaxf(s[2][0], s[2][1]), fmaxf(s[2][2], s[2][3]));
            float mD = fmaxf(fmaxf(s[3][0], s[3][1]), fmaxf(s[3][2], s[3][3]));
            float mx = fmaxf(fmaxf(mA, mB), fmaxf(mC, mD));
            mx = fmaxf(mx, __shfl_xor(mx, 16, 64));
            mx = fmaxf(mx, __shfl_xor(mx, 32, 64));
            const float mnew  = fmaxf(m_run, mx);
            const float alpha = __builtin_amdgcn_exp2f(m_run - mnew);
            m_run = mnew;
#pragma unroll
            for (int sub = 0; sub < 4; ++sub)
#pragma unroll
                for (int r = 0; r < 4; ++r)
                    s[sub][r] = __builtin_amdgcn_exp2f(s[sub][r] - mnew);
            o_l[0] *= alpha;
#pragma unroll
            for (int dt = 0; dt < 4; ++dt)
#pragma unroll
                for (int r = 0; r < 4; ++r) o[dt][r] *= alpha;

            // ---- P -> per-wave LDS, packed key-pair b32 writes
#pragma unroll
            for (int sub = 0; sub < 4; ++sub) {
                const int kc = sub * 16 + quad * 4;
                *(unsigned int*)&Ps[wave][l16][kc]     = pack2((bf16)s[sub][0], (bf16)s[sub][1]);
                *(unsigned int*)&Ps[wave][l16][kc + 2] = pack2((bf16)s[sub][2], (bf16)s[sub][3]);
            }
            __asm__ volatile("" ::: "memory");   // keep reads below writes

            bf16x8 pb0 = *(const bf16x8*)&Ps[wave][l16][quad * 8];
            bf16x8 pb1 = *(const bf16x8*)&Ps[wave][l16][32 + quad * 8];

            // ---- O^T += V^T * P ; l += ones-row * P
#pragma unroll
            for (int kb = 0; kb < 2; ++kb) {
                const int kcol = kb * 32 + quad * 8;
                const bf16x8 pb = kb ? pb1 : pb0;
#pragma unroll
                for (int dt = 0; dt < 4; ++dt) {
                    const int d = dt * 16 + l16;
                    bf16x8 vf = *(const bf16x8*)&Vt[d][kcol ^ vswz(d)];
                    o[dt] = MFMA16(vf, pb, o[dt]);
                }
                o_l = MFMA16(ones, pb, o_l);
            }
        }

        // ---- recover l (lane l16 of quad 0 holds l[q=l16]), normalize, write
        const float lq  = __shfl(o_l[0], l16, 64);
        const float inv = 1.f / lq;
        bf16* yrow = y + (size_t)(b * Ts + qw + l16) * DM + h * HS;
#pragma unroll
        for (int dt = 0; dt < 4; ++dt) {
            bf16x4 ov;
#pragma unroll
            for (int r = 0; r < 4; ++r) ov[r] = (bf16)(o[dt][r] * inv);
            *(bf16x4*)(yrow + dt * 16 + quad * 4) = ov;
        }
    }
}

// ---------------------------------------------------------------------------
extern "C" void kernel_launch(void* const* d_in, const int* in_sizes, int n_in,
                              void* d_out, int out_size, void* d_ws, size_t ws_size,
                              hipStream_t stream)
{
    const float* x     = (const float*)d_in[0];
    const float* Wqkv  = (const float*)d_in[1];
    const float* bqkv  = (const float*)d_in[2];
    const float* Wproj = (const float*)d_in[3];
    const float* bproj = (const float*)d_in[4];

    char* ws = (char*)d_ws;
    bf16* xb     = (bf16*)ws;  ws += (size_t)MROWS * DM * 2;
    bf16* wqkvb  = (bf16*)ws;  ws += (size_t)NQKV * DM * 2;
    bf16* wprojb = (bf16*)ws;  ws += (size_t)DM * DM * 2;
    bf16* qkvb   = (bf16*)ws;  ws += (size_t)MROWS * NQKV * 2;
    bf16* yb     = (bf16*)ws;

    cvt_kernel<<<MROWS * DM / 4 / 256, 256, 0, stream>>>(x, xb, MROWS * DM / 4);
    cvt_kernel<<<NQKV * DM / 4 / 256, 256, 0, stream>>>(Wqkv, wqkvb, NQKV * DM / 4);
    cvt_kernel<<<DM * DM / 4 / 256, 256, 0, stream>>>(Wproj, wprojb, DM * DM / 4);

    gemm_bt<1><<<dim3(MROWS / 128, NQKV / 128), 256, 0, stream>>>(
        xb, wqkvb, bqkv, qkvb, MROWS, NQKV, DM, QSCALE, DM);

    attn_kernel<<<dim3(16, NH, Bz), 256, 0, stream>>>(qkvb, yb);

    gemm_bt<0><<<dim3(MROWS / 128, DM / 128), 256, 0, stream>>>(
        yb, wprojb, bproj, d_out, MROWS, DM, DM, 1.0f, 0);
}

// Round 8
// 272.837 us; speedup vs baseline: 1.0668x; 1.0668x over previous
//
#include <hip/hip_runtime.h>
#include <math.h>

typedef __bf16 bf16;
typedef __bf16 bf16x4 __attribute__((ext_vector_type(4)));
typedef __bf16 bf16x8 __attribute__((ext_vector_type(8)));
typedef float  f32x4  __attribute__((ext_vector_type(4)));
typedef unsigned short u16;

#define MFMA16(a, b, c) __builtin_amdgcn_mfma_f32_16x16x32_bf16((a), (b), (c), 0, 0, 0)

constexpr int Bz    = 4;
constexpr int Ts    = 2048;
constexpr int DM    = 1024;
constexpr int NH    = 16;
constexpr int HS    = 64;
constexpr int MROWS = Bz * Ts;   // 8192
constexpr int NQKV  = 3 * DM;    // 3072

// float4-chunk counts for the fused convert kernel
constexpr int NX4  = MROWS * DM / 4;    // 2097152
constexpr int NW14 = NQKV * DM / 4;     //  786432
constexpr int NW24 = DM * DM / 4;       //  262144

// 0.125 (1/sqrt(64)) * log2(e): folded into Q at the QKV-GEMM epilogue.
#define QSCALE 0.18033688011112042f

__device__ __forceinline__ unsigned int pack2(bf16 lo, bf16 hi) {
    return ((unsigned int)__builtin_bit_cast(u16, hi) << 16) |
            (unsigned int)__builtin_bit_cast(u16, lo);
}

// ---------------------------------------------------------------------------
__device__ __forceinline__ void load_lds16(const bf16* g, bf16* l) {
    __builtin_amdgcn_global_load_lds(
        (__attribute__((address_space(1))) void*)(g),
        (__attribute__((address_space(3))) void*)(l), 16, 0, 0);
}

// ---------------------------------------------------------------------------
// Fused fp32->bf16 conversion for x, W_qkv, W_proj in one launch.
// All three ranges are multiples of 256 -> branch is block-uniform.
__global__ __launch_bounds__(256) void cvt3_kernel(const float* __restrict__ x,   bf16* __restrict__ xb,
                                                   const float* __restrict__ w1,  bf16* __restrict__ w1b,
                                                   const float* __restrict__ w2,  bf16* __restrict__ w2b)
{
    int i = blockIdx.x * 256 + threadIdx.x;
    const float* in; bf16* out;
    if (i < NX4)              { in = x;  out = xb;  }
    else if (i < NX4 + NW14)  { in = w1; out = w1b; i -= NX4; }
    else                      { in = w2; out = w2b; i -= NX4 + NW14; }
    float4 v = ((const float4*)in)[i];
    bf16x4 o = { (bf16)v.x, (bf16)v.y, (bf16)v.z, (bf16)v.w };
    ((bf16x4*)out)[i] = o;
}

// ---------------------------------------------------------------------------
// C = A * B^T + bias.  128x128 tile, BK=32, 256 threads (m97 structure).
// Columns < qcols additionally scaled by qscale (Q pre-scaling; wave-uniform).
template <int OUT_BF16>
__global__ __launch_bounds__(256) void gemm_bt(const bf16* __restrict__ A,
                                               const bf16* __restrict__ Bw,
                                               const float* __restrict__ bias,
                                               void* __restrict__ Cout,
                                               int M, int N, int K,
                                               float qscale, int qcols)
{
    __shared__ __align__(16) bf16 As[128 * 32];
    __shared__ __align__(16) bf16 Bs[128 * 32];

    const int tid  = threadIdx.x;
    const int wave = tid >> 6, lane = tid & 63;
    const int quad = lane >> 4, l16 = lane & 15;
    const int wm = (wave >> 1) * 64, wn = (wave & 1) * 64;
    const int m0 = blockIdx.x * 128, n0 = blockIdx.y * 128;

    f32x4 acc[4][4] = {};

    const int c0 = tid, c1 = tid + 256;
    const bf16* gA0 = A  + (size_t)(m0 + (c0 >> 2)) * K + (c0 & 3) * 8;
    const bf16* gA1 = A  + (size_t)(m0 + (c1 >> 2)) * K + (c1 & 3) * 8;
    const bf16* gB0 = Bw + (size_t)(n0 + (c0 >> 2)) * K + (c0 & 3) * 8;
    const bf16* gB1 = Bw + (size_t)(n0 + (c1 >> 2)) * K + (c1 & 3) * 8;
    bf16* lA0 = As + c0 * 8;  bf16* lA1 = As + c1 * 8;
    bf16* lB0 = Bs + c0 * 8;  bf16* lB1 = Bs + c1 * 8;

    for (int kb = 0; kb < K; kb += 32) {
        if (kb) __syncthreads();
        load_lds16(gA0 + kb, lA0);
        load_lds16(gA1 + kb, lA1);
        load_lds16(gB0 + kb, lB0);
        load_lds16(gB1 + kb, lB1);
        __syncthreads();

        bf16x8 af[4], bfr[4];
#pragma unroll
        for (int mt = 0; mt < 4; ++mt)
            af[mt] = *(const bf16x8*)(As + (wm + mt * 16 + l16) * 32 + quad * 8);
#pragma unroll
        for (int nt = 0; nt < 4; ++nt)
            bfr[nt] = *(const bf16x8*)(Bs + (wn + nt * 16 + l16) * 32 + quad * 8);
#pragma unroll
        for (int mt = 0; mt < 4; ++mt)
#pragma unroll
            for (int nt = 0; nt < 4; ++nt)
                acc[mt][nt] = MFMA16(af[mt], bfr[nt], acc[mt][nt]);
    }

#pragma unroll
    for (int mt = 0; mt < 4; ++mt)
#pragma unroll
        for (int nt = 0; nt < 4; ++nt) {
            const int row = m0 + wm + mt * 16 + quad * 4;
            const int col = n0 + wn + nt * 16 + l16;
            const float bc = bias[col];
            const float sc = (col < qcols) ? qscale : 1.0f;
#pragma unroll
            for (int r = 0; r < 4; ++r) {
                const float v = (acc[mt][nt][r] + bc) * sc;
                if (OUT_BF16) ((bf16*)Cout)[(size_t)(row + r) * N + col] = (bf16)v;
                else          ((float*)Cout)[(size_t)(row + r) * N + col] = v;
            }
        }
}

// ---------------------------------------------------------------------------
// Vt key-block swizzle keyed on d>>3: conflict-minimal for the packed b32
// transpose-write and the b128 PV read. (round-5-verified)
__device__ __forceinline__ int vswz(int d) { return ((d >> 3) & 7) << 3; }

// Flash attention, S^T formulation — EXACT round-5 configuration (97 us known:
// 64-key tiles, 27.6 KB LDS, 2 barriers/iter; r6 bigger-tile and r7 pipelining
// variants both measured SLOWER due to occupancy/structure).
__global__ __launch_bounds__(256) void attn_kernel(const bf16* __restrict__ qkv,
                                                   bf16* __restrict__ y)
{
    __shared__ __align__(16) bf16 Ks[64][72];      // [key][d]
    __shared__ __align__(16) bf16 Vt[64][72];      // [d][key ^ vswz(d)]
    __shared__ __align__(16) bf16 Ps[4][16][72];   // per-wave [q=l16][key]

    const int p = blockIdx.x, h = blockIdx.y, b = blockIdx.z;
    const int tid  = threadIdx.x;
    const int wave = tid >> 6, lane = tid & 63;
    const int quad = lane >> 4, l16 = lane & 15;

    const bf16* kbase = qkv + (size_t)(b * Ts) * NQKV + DM     + h * HS;
    const bf16* vbase = qkv + (size_t)(b * Ts) * NQKV + 2 * DM + h * HS;

    const int dg = tid & 7, kp = tid >> 3;   // V staging mapping
    const int k0 = 2 * kp;

    for (int phase = 0; phase < 2; ++phase) {
        const int qt = phase ? (31 - p) : p;
        const int qw = qt * 64 + wave * 16;
        const int q_abs = qw + l16;

        const bf16* qrow = qkv + (size_t)(b * Ts + qw + l16) * NQKV + h * HS;
        const bf16x8 qf0 = *(const bf16x8*)(qrow + quad * 8);
        const bf16x8 qf1 = *(const bf16x8*)(qrow + 32 + quad * 8);

        f32x4 o[4] = {};            // O^T[d = dt*16 + quad*4 + r][q = l16]
        float m_run = -1e30f, l_run = 0.f;

        auto iter = [&](int kt, bool masked) {
            __syncthreads();   // prior iter's Ks/Vt reads complete

            // ---- stage K [64x64] natural, b128 writes
            {
                int e = tid * 8;
#pragma unroll
                for (int rr = 0; rr < 2; ++rr, e += 2048) {
                    const int key = e >> 6, c = e & 63;
                    bf16x8 kv = *(const bf16x8*)(kbase + (size_t)(kt * 64 + key) * NQKV + c);
                    *(bf16x8*)&Ks[key][c] = kv;
                }
            }
            // ---- stage V transposed: key-pair packed b32 writes
            {
                const bf16x8 v0 = *(const bf16x8*)(vbase + (size_t)(kt * 64 + k0)     * NQKV + dg * 8);
                const bf16x8 v1 = *(const bf16x8*)(vbase + (size_t)(kt * 64 + k0 + 1) * NQKV + dg * 8);
#pragma unroll
                for (int j = 0; j < 8; ++j) {
                    const int d = dg * 8 + j;
                    *(unsigned int*)&Vt[d][k0 ^ vswz(d)] = pack2(v0[j], v1[j]);
                }
            }
            __syncthreads();

            // ---- S^T (log2 domain, scale pre-folded into Q)
            f32x4 s[4];
#pragma unroll
            for (int sub = 0; sub < 4; ++sub) {
                bf16x8 kf0 = *(const bf16x8*)&Ks[sub * 16 + l16][quad * 8];
                bf16x8 kf1 = *(const bf16x8*)&Ks[sub * 16 + l16][32 + quad * 8];
                f32x4 z = {};
                z = MFMA16(kf0, qf0, z);
                z = MFMA16(kf1, qf1, z);
                s[sub] = z;
            }

            // ---- causal mask: only the diagonal tile needs it
            if (masked) {
#pragma unroll
                for (int sub = 0; sub < 4; ++sub) {
                    const int kb = kt * 64 + sub * 16 + quad * 4;
#pragma unroll
                    for (int r = 0; r < 4; ++r)
                        if (kb + r > q_abs) s[sub][r] = -1e30f;
                }
            }

            // ---- online softmax (log2 domain): balanced trees + 2 shfls
            float mA = fmaxf(fmaxf(s[0][0], s[0][1]), fmaxf(s[0][2], s[0][3]));
            float mB = fmaxf(fmaxf(s[1][0], s[1][1]), fmaxf(s[1][2], s[1][3]));
            float mC = fmaxf(fmaxf(s[2][0], s[2][1]), fmaxf(s[2][2], s[2][3]));
            float mD = fmaxf(fmaxf(s[3][0], s[3][1]), fmaxf(s[3][2], s[3][3]));
            float mx = fmaxf(fmaxf(mA, mB), fmaxf(mC, mD));
            mx = fmaxf(mx, __shfl_xor(mx, 16, 64));
            mx = fmaxf(mx, __shfl_xor(mx, 32, 64));
            const float mnew  = fmaxf(m_run, mx);
            const float alpha = __builtin_amdgcn_exp2f(m_run - mnew);
#pragma unroll
            for (int sub = 0; sub < 4; ++sub)
#pragma unroll
                for (int r = 0; r < 4; ++r)
                    s[sub][r] = __builtin_amdgcn_exp2f(s[sub][r] - mnew);
            float t0 = (s[0][0] + s[0][1]) + (s[0][2] + s[0][3]);
            float t1 = (s[1][0] + s[1][1]) + (s[1][2] + s[1][3]);
            float t2 = (s[2][0] + s[2][1]) + (s[2][2] + s[2][3]);
            float t3 = (s[3][0] + s[3][1]) + (s[3][2] + s[3][3]);
            float ls = (t0 + t1) + (t2 + t3);
            ls += __shfl_xor(ls, 16, 64);
            ls += __shfl_xor(ls, 32, 64);
            l_run = l_run * alpha + ls;
            m_run = mnew;
#pragma unroll
            for (int dt = 0; dt < 4; ++dt)
#pragma unroll
                for (int r = 0; r < 4; ++r) o[dt][r] *= alpha;

            // ---- P -> per-wave LDS [q=l16][key], packed key-pair b32 writes
#pragma unroll
            for (int sub = 0; sub < 4; ++sub) {
                const int kc = sub * 16 + quad * 4;
                *(unsigned int*)&Ps[wave][l16][kc]     = pack2((bf16)s[sub][0], (bf16)s[sub][1]);
                *(unsigned int*)&Ps[wave][l16][kc + 2] = pack2((bf16)s[sub][2], (bf16)s[sub][3]);
            }
            __asm__ volatile("" ::: "memory");   // keep reads below writes

            bf16x8 pb0 = *(const bf16x8*)&Ps[wave][l16][quad * 8];
            bf16x8 pb1 = *(const bf16x8*)&Ps[wave][l16][32 + quad * 8];

            // ---- O^T += V^T * P
#pragma unroll
            for (int kb = 0; kb < 2; ++kb) {
                const int kcol = kb * 32 + quad * 8;
#pragma unroll
                for (int dt = 0; dt < 4; ++dt) {
                    const int d = dt * 16 + l16;
                    bf16x8 vf = *(const bf16x8*)&Vt[d][kcol ^ vswz(d)];
                    o[dt] = MFMA16(vf, kb ? pb1 : pb0, o[dt]);
                }
            }
        };

        for (int kt = 0; kt < qt; ++kt) iter(kt, false);
        iter(qt, true);

        // ---- normalize + write
        const float inv = 1.f / l_run;
        bf16* yrow = y + (size_t)(b * Ts + qw + l16) * DM + h * HS;
#pragma unroll
        for (int dt = 0; dt < 4; ++dt) {
            bf16x4 ov;
#pragma unroll
            for (int r = 0; r < 4; ++r) ov[r] = (bf16)(o[dt][r] * inv);
            *(bf16x4*)(yrow + dt * 16 + quad * 4) = ov;
        }
    }
}

// ---------------------------------------------------------------------------
extern "C" void kernel_launch(void* const* d_in, const int* in_sizes, int n_in,
                              void* d_out, int out_size, void* d_ws, size_t ws_size,
                              hipStream_t stream)
{
    const float* x     = (const float*)d_in[0];
    const float* Wqkv  = (const float*)d_in[1];
    const float* bqkv  = (const float*)d_in[2];
    const float* Wproj = (const float*)d_in[3];
    const float* bproj = (const float*)d_in[4];

    char* ws = (char*)d_ws;
    bf16* xb     = (bf16*)ws;  ws += (size_t)MROWS * DM * 2;
    bf16* wqkvb  = (bf16*)ws;  ws += (size_t)NQKV * DM * 2;
    bf16* wprojb = (bf16*)ws;  ws += (size_t)DM * DM * 2;
    bf16* qkvb   = (bf16*)ws;  ws += (size_t)MROWS * NQKV * 2;
    bf16* yb     = (bf16*)ws;

    cvt3_kernel<<<(NX4 + NW14 + NW24) / 256, 256, 0, stream>>>(
        x, xb, Wqkv, wqkvb, Wproj, wprojb);

    gemm_bt<1><<<dim3(MROWS / 128, NQKV / 128), 256, 0, stream>>>(
        xb, wqkvb, bqkv, qkvb, MROWS, NQKV, DM, QSCALE, DM);

    attn_kernel<<<dim3(16, NH, Bz), 256, 0, stream>>>(qkvb, yb);

    gemm_bt<0><<<dim3(MROWS / 128, DM / 128), 256, 0, stream>>>(
        yb, wprojb, bproj, d_out, MROWS, DM, DM, 1.0f, 0);
}